// Round 18
// baseline (48.662 us; speedup 1.0000x reference)
//
#include <hip/hip_runtime.h>
#include <hip/hip_fp16.h>
#include <math.h>

#define KPTS 133
#define FPS  (KPTS * 3)          // 399 floats per sample
#define SPB  8                   // samples per block (256 thr, 2 per wave)
#define SPWV 2                   // samples per wave (32 lanes each)

// DPP quad_perm shuffles: VALU-only (no LDS pipe, no lgkmcnt latency)
#define DPP_XOR1(x) __int_as_float(__builtin_amdgcn_update_dpp(0, __float_as_int(x), 0xB1, 0xF, 0xF, true))
#define DPP_XOR2(x) __int_as_float(__builtin_amdgcn_update_dpp(0, __float_as_int(x), 0x4E, 0xF, 0xF, true))

// Opaque register pin: forbids rematerializing the producing loads.
#define PINU(x) asm volatile("" : "+v"(x))

__device__ __forceinline__ float2 f2(float a, float b) { return make_float2(a, b); }

// fp16 pack/unpack (round-to-nearest; validated R15/R16: absmax 0.0)
__device__ __forceinline__ unsigned pack2h(float a, float b) {
    __half2 h = __float22half2_rn(make_float2(a, b));
    union { __half2 h; unsigned u; } c; c.h = h; return c.u;
}
__device__ __forceinline__ float2 unpack2h(unsigned u) {
    union { unsigned u; __half2 h; } c; c.u = u;
    return make_float2(__half2float(__low2half(c.h)), __half2float(__high2half(c.h)));
}

__device__ __forceinline__ float det3(float a0, float a1, float a2,
                                      float b0, float b1, float b2,
                                      float c0, float c1, float c2) {
    return a0 * (b1 * c2 - b2 * c1)
         - a1 * (b0 * c2 - b2 * c0)
         + a2 * (b0 * c1 - b1 * c0);
}

// R18 = R17 with 32 lanes/sample (2 samples/wave): points/lane 8+1 -> 4+1,
// pinned uints 27 -> 15, total regs ~80 -> ~6 waves/SIMD (vs 4.6). The
// latency-bound profile (VALU 48%, HBM 40%, occ 37%, nothing saturated)
// says occupancy is the binding constraint; this buys ~1.3x more latency
// hiding at the cost of +1 butterfly stage and 8x (vs 16x) solve amortize.
__global__ __launch_bounds__(256, 4) void pa_mpjpe_kernel(
    const float* __restrict__ outp,   // (N,K,3) output
    const float* __restrict__ tgtp,   // (N,K,3) target
    float* __restrict__ block_sums,
    int nsamp)
{
    const int tid  = threadIdx.x;
    const int lane = tid & 63;
    const int wid  = tid >> 6;
    const int l32  = lane & 31;
    const int l16  = lane & 15;
    const int s_l  = wid * SPWV + (lane >> 5);   // local sample 0..7
    int s = blockIdx.x * SPB + s_l;
    const bool valid = (s < nsamp);
    if (!valid) s = 0;                           // clamp; zeroed later

    __shared__ float momT[SPB][17];
    __shared__ float prm[SPB][13];
    __shared__ float shs[SPB];

    const float3* tb3 = reinterpret_cast<const float3*>(tgtp + (size_t)s * FPS);
    const float3* ob3 = reinterpret_cast<const float3*>(outp + (size_t)s * FPS);

    // ---- load points (dwordx3), accumulate fp32 moments, pack to half2 ----
    float2 P0 = f2(0,0), P1 = f2(0,0), P2 = f2(0,0), P3 = f2(0,0);
    float2 P4 = f2(0,0), P5 = f2(0,0), P6 = f2(0,0), P7 = f2(0,0);
    float2 Q  = f2(0,0);

#define DECLPT(k) unsigned uT_##k = 0u, uM_##k = 0u, uO_##k = 0u;
#define LOADACC(k, P) {                                                     \
    const float3 t = tb3[(P)];                                              \
    const float3 o = ob3[(P)];                                              \
    P0 += f2(t.x, t.y);                                                     \
    P1 += f2(t.z, o.x);                                                     \
    P2 += f2(o.y, o.z);                                                     \
    P3 += f2(t.x, t.x) * f2(o.x, o.y);                                      \
    P4 += f2(t.x, t.y) * f2(o.z, o.x);                                      \
    P5 += f2(t.y, t.y) * f2(o.y, o.z);                                      \
    P6 += f2(t.z, t.z) * f2(o.x, o.y);                                      \
    P7 += f2(t.z, t.x) * f2(o.z, t.x);                                      \
    Q  += f2(t.y, t.z) * f2(t.y, t.z);                                      \
    uT_##k = pack2h(t.x, t.y);                                              \
    uM_##k = pack2h(t.z, o.x);                                              \
    uO_##k = pack2h(o.y, o.z);                                              \
}
#define PINPT(k) PINU(uT_##k); PINU(uM_##k); PINU(uO_##k);

    DECLPT(0) DECLPT(1) DECLPT(2) DECLPT(3) DECLPT(4)

    LOADACC(0, l32 +  0)
    LOADACC(1, l32 + 32)
    LOADACC(2, l32 + 64)
    LOADACC(3, l32 + 96)
    if (l32 < 5) {
        LOADACC(4, 128 + l32)
    }

    // pin packed points: live across butterfly + solve + barriers
    PINPT(0) PINPT(1) PINPT(2) PINPT(3) PINPT(4)

    float red[16];
    red[0]  = P0.x; red[1]  = P0.y; red[2]  = P1.x; red[3]  = P1.y;
    red[4]  = P2.x; red[5]  = P2.y; red[6]  = P3.x; red[7]  = P3.y;
    red[8]  = P4.x; red[9]  = P4.y; red[10] = P5.x; red[11] = P5.y;
    red[12] = P6.x; red[13] = P6.y; red[14] = P7.x; red[15] = P7.y + Q.x + Q.y;

    // ---- value-splitting butterfly (4 halving stages) + xor16 stage ----
    // After xor1..8: lane l holds its 16-lane cohort's sum of red[l&15];
    // xor16 merges the two cohorts of the 32-lane group.
    float v8[8];
    {
        const bool b = (lane & 1);
        #pragma unroll
        for (int m = 0; m < 8; ++m) {
            const float snd = b ? red[2 * m] : red[2 * m + 1];
            const float rcv = DPP_XOR1(snd);
            v8[m] = (b ? red[2 * m + 1] : red[2 * m]) + rcv;
        }
    }
    float v4_[4];
    {
        const bool b = ((lane >> 1) & 1);
        #pragma unroll
        for (int m = 0; m < 4; ++m) {
            const float snd = b ? v8[2 * m] : v8[2 * m + 1];
            const float rcv = DPP_XOR2(snd);
            v4_[m] = (b ? v8[2 * m + 1] : v8[2 * m]) + rcv;
        }
    }
    float v2_[2];
    {
        const bool b = ((lane >> 2) & 1);
        #pragma unroll
        for (int m = 0; m < 2; ++m) {
            const float snd = b ? v4_[2 * m] : v4_[2 * m + 1];
            const float rcv = __shfl_xor(snd, 4, 64);
            v2_[m] = (b ? v4_[2 * m + 1] : v4_[2 * m]) + rcv;
        }
    }
    float v1;
    {
        const bool b = ((lane >> 3) & 1);
        const float snd = b ? v2_[0] : v2_[1];
        const float rcv = __shfl_xor(snd, 8, 64);
        v1 = (b ? v2_[1] : v2_[0]) + rcv;
    }
    v1 += __shfl_xor(v1, 16, 64);   // complete 32-lane group sum

    if (l32 < 16) momT[s_l][l16] = v1;
    __syncthreads();

    // ---- solve: wave 0, lanes 0..7, one sample each (8x amortized) ----
    if (wid == 0 && lane < SPB && (blockIdx.x * SPB + lane) < nsamp) {
        float m_[16];
        #pragma unroll
        for (int j = 0; j < 16; ++j) m_[j] = momT[lane][j];

        const float invK = 1.0f / (float)KPTS;
        const float mu1x = m_[0] * invK, mu1y = m_[1] * invK, mu1z = m_[2] * invK;
        const float mu2x = m_[3] * invK, mu2y = m_[4] * invK, mu2z = m_[5] * invK;

        const float Sxx = m_[6]  - m_[0] * m_[3] * invK;
        const float Sxy = m_[7]  - m_[0] * m_[4] * invK;
        const float Sxz = m_[8]  - m_[0] * m_[5] * invK;
        const float Syx = m_[9]  - m_[1] * m_[3] * invK;
        const float Syy = m_[10] - m_[1] * m_[4] * invK;
        const float Syz = m_[11] - m_[1] * m_[5] * invK;
        const float Szx = m_[12] - m_[2] * m_[3] * invK;
        const float Szy = m_[13] - m_[2] * m_[4] * invK;
        const float Szz = m_[14] - m_[2] * m_[5] * invK;
        const float var1 = m_[15] - (m_[0] * m_[0] + m_[1] * m_[1] + m_[2] * m_[2]) * invK;

        const float N00 = Sxx + Syy + Szz;
        const float N01 = Syz - Szy, N02 = Szx - Sxz, N03 = Sxy - Syx;
        const float N11 = Sxx - Syy - Szz, N12 = Sxy + Syx, N13 = Szx + Sxz;
        const float N22 = -Sxx + Syy - Szz, N23 = Syz + Szy;
        const float N33 = -Sxx - Syy + Szz;

        const float trKtK = Sxx * Sxx + Sxy * Sxy + Sxz * Sxz
                          + Syx * Syx + Syy * Syy + Syz * Syz
                          + Szx * Szx + Szy * Szy + Szz * Szz;
        const float c2 = -2.0f * trKtK;
        const float detK = det3(Sxx, Sxy, Sxz, Syx, Syy, Syz, Szx, Szy, Szz);
        const float c1 = -8.0f * detK;
        const float c0 =
              N00 * det3(N11, N12, N13, N12, N22, N23, N13, N23, N33)
            - N01 * det3(N01, N12, N13, N02, N22, N23, N03, N23, N33)
            + N02 * det3(N01, N11, N13, N02, N12, N23, N03, N13, N33)
            - N03 * det3(N01, N11, N12, N02, N12, N22, N03, N13, N23);

        float lam = sqrtf(fmaxf(3.0f * trKtK, 0.0f));
        #pragma unroll
        for (int it = 0; it < 10; ++it) {
            const float l2 = lam * lam;
            const float P  = (l2 + c2) * l2 + c1 * lam + c0;
            const float Pp = (4.0f * l2 + 2.0f * c2) * lam + c1;
            lam -= P / Pp;
        }

        const float M00 = N00 - lam, M11 = N11 - lam, M22 = N22 - lam, M33 = N33 - lam;
        const float a0 =  det3(M11, N12, N13, N12, M22, N23, N13, N23, M33);
        const float a1 = -det3(N01, N12, N13, N02, M22, N23, N03, N23, M33);
        const float a2 =  det3(N01, M11, N13, N02, N12, N23, N03, N13, M33);
        const float a3 = -det3(N01, M11, N12, N02, N12, M22, N03, N13, N23);
        const float b0 = -det3(N01, N02, N03, N12, M22, N23, N13, N23, M33);
        const float b1 =  det3(M00, N02, N03, N02, M22, N23, N03, N23, M33);
        const float b2 = -det3(M00, N01, N03, N02, N12, N23, N03, N13, M33);
        const float b3 =  det3(M00, N01, N02, N02, N12, M22, N03, N13, N23);
        const float na = a0 * a0 + a1 * a1 + a2 * a2 + a3 * a3;
        const float nb = b0 * b0 + b1 * b1 + b2 * b2 + b3 * b3;
        const bool pa_ = (na >= nb);
        float qw = pa_ ? a0 : b0;
        float qx = pa_ ? a1 : b1;
        float qy = pa_ ? a2 : b2;
        float qz = pa_ ? a3 : b3;
        const float qn = rsqrtf(fmaxf(qw * qw + qx * qx + qy * qy + qz * qz, 1e-30f));
        qw *= qn; qx *= qn; qy *= qn; qz *= qn;

        const float R00 = 1.0f - 2.0f * (qy * qy + qz * qz);
        const float R01 = 2.0f * (qx * qy - qw * qz);
        const float R02 = 2.0f * (qx * qz + qw * qy);
        const float R10 = 2.0f * (qx * qy + qw * qz);
        const float R11 = 1.0f - 2.0f * (qx * qx + qz * qz);
        const float R12 = 2.0f * (qy * qz - qw * qx);
        const float R20 = 2.0f * (qx * qz - qw * qy);
        const float R21 = 2.0f * (qy * qz + qw * qx);
        const float R22 = 1.0f - 2.0f * (qx * qx + qy * qy);

        const float trRK = R00 * Sxx + R01 * Syx + R02 * Szx
                         + R10 * Sxy + R11 * Syy + R12 * Szy
                         + R20 * Sxz + R21 * Syz + R22 * Szz;
        const float scale = trRK / var1;

        const float tx = mu2x - scale * (R00 * mu1x + R01 * mu1y + R02 * mu1z);
        const float ty = mu2y - scale * (R10 * mu1x + R11 * mu1y + R12 * mu1z);
        const float tz = mu2z - scale * (R20 * mu1x + R21 * mu1y + R22 * mu1z);

        prm[lane][0] = scale * R00; prm[lane][1] = scale * R01; prm[lane][2] = scale * R02;
        prm[lane][3] = scale * R10; prm[lane][4] = scale * R11; prm[lane][5] = scale * R12;
        prm[lane][6] = scale * R20; prm[lane][7] = scale * R21; prm[lane][8] = scale * R22;
        prm[lane][9] = tx; prm[lane][10] = ty; prm[lane][11] = tz;
    }
    __syncthreads();

    // ---- residuals from fp16-packed pinned registers (no second pass) ----
    const float2 rA = f2(prm[s_l][0], prm[s_l][3]);   // (sR00, sR10)
    const float2 rB = f2(prm[s_l][1], prm[s_l][4]);   // (sR01, sR11)
    const float2 rC = f2(prm[s_l][2], prm[s_l][5]);   // (sR02, sR12)
    const float sR20 = prm[s_l][6], sR21 = prm[s_l][7], sR22 = prm[s_l][8];
    const float2 txy = f2(prm[s_l][9], prm[s_l][10]);
    const float tz = prm[s_l][11];

    float rsum = 0.0f;
#define RESPT(k)                                                            \
    {                                                                       \
        const float2 pT = unpack2h(uT_##k);   /* t0, t1 */                  \
        const float2 pM = unpack2h(uM_##k);   /* t2, o0 */                  \
        const float2 pO = unpack2h(uO_##k);   /* o1, o2 */                  \
        float2 axy = txy;                                                   \
        axy += rA * f2(pT.x, pT.x);                                         \
        axy += rB * f2(pT.y, pT.y);                                         \
        axy += rC * f2(pM.x, pM.x);                                         \
        const float az = fmaf(sR20, pT.x, fmaf(sR21, pT.y, fmaf(sR22, pM.x, tz))); \
        const float2 dxy = f2(pM.y, pO.x) - axy;                            \
        const float dz = pO.y - az;                                         \
        const float ns = fmaf(dxy.x, dxy.x, fmaf(dxy.y, dxy.y, dz * dz));   \
        rsum += sqrtf(ns);                                                  \
    }

    RESPT(0) RESPT(1) RESPT(2) RESPT(3)
    if (l32 < 5) { RESPT(4) }

    rsum = valid ? rsum : 0.0f;

    // 32-lane group sum
    rsum += DPP_XOR1(rsum);
    rsum += DPP_XOR2(rsum);
    rsum += __shfl_xor(rsum, 4, 64);
    rsum += __shfl_xor(rsum, 8, 64);
    rsum += __shfl_xor(rsum, 16, 64);

    if (l32 == 0) shs[s_l] = rsum;
    __syncthreads();
    if (tid == 0) {
        float b = 0.0f;
        #pragma unroll
        for (int i = 0; i < SPB; ++i) b += shs[i];
        block_sums[blockIdx.x] = b;
    }
}

// Deterministic final reduction: one block, fixed order, 4-way ILP.
__global__ __launch_bounds__(256) void pa_reduce_kernel(
    const float* __restrict__ block_sums, int n,
    float* __restrict__ out, float inv_total)
{
    __shared__ float sh[4];
    float a0 = 0.f, a1 = 0.f, a2 = 0.f, a3 = 0.f;
    for (int i = (int)threadIdx.x * 4; i < n; i += 1024) {
        if (i + 0 < n) a0 += block_sums[i + 0];
        if (i + 1 < n) a1 += block_sums[i + 1];
        if (i + 2 < n) a2 += block_sums[i + 2];
        if (i + 3 < n) a3 += block_sums[i + 3];
    }
    float v = (a0 + a1) + (a2 + a3);
    #pragma unroll
    for (int off = 32; off >= 1; off >>= 1) v += __shfl_xor(v, off, 64);
    const int lane = threadIdx.x & 63;
    const int wid  = threadIdx.x >> 6;
    if (lane == 0) sh[wid] = v;
    __syncthreads();
    if (threadIdx.x == 0) out[0] = (sh[0] + sh[1] + sh[2] + sh[3]) * inv_total;
}

extern "C" void kernel_launch(void* const* d_in, const int* in_sizes, int n_in,
                              void* d_out, int out_size, void* d_ws, size_t ws_size,
                              hipStream_t stream) {
    const float* outp = (const float*)d_in[0];   // "output"
    const float* tgtp = (const float*)d_in[1];   // "target"
    const int nsamp   = in_sizes[0] / FPS;
    const int nblocks = (nsamp + SPB - 1) / SPB;

    float* bsums = (float*)d_ws;

    pa_mpjpe_kernel<<<nblocks, 256, 0, stream>>>(outp, tgtp, bsums, nsamp);
    pa_reduce_kernel<<<1, 256, 0, stream>>>(
        bsums, nblocks, (float*)d_out,
        1.0f / ((float)nsamp * (float)KPTS));
}

// Round 19
// 41.073 us; speedup vs baseline: 1.1848x; 1.1848x over previous
//
#include <hip/hip_runtime.h>
#include <hip/hip_fp16.h>
#include <math.h>

#define KPTS 133
#define FPS  (KPTS * 3)          // 399 floats per sample
#define SPB  16                  // samples per block
#define SPWV 4                   // samples per wave (16 lanes each)

// DPP quad_perm shuffles: VALU-only (no LDS pipe, no lgkmcnt latency)
#define DPP_XOR1(x) __int_as_float(__builtin_amdgcn_update_dpp(0, __float_as_int(x), 0xB1, 0xF, 0xF, true))
#define DPP_XOR2(x) __int_as_float(__builtin_amdgcn_update_dpp(0, __float_as_int(x), 0x4E, 0xF, 0xF, true))

// Opaque register pin: requires the value in a VGPR at this point and forbids
// rematerializing the producing loads. The allocator parks the live range in
// AGPRs at launch_bounds(256,4) (R14/R16-verified: no scratch spill).
#define PINU(x) asm volatile("" : "+v"(x))

__device__ __forceinline__ float2 f2(float a, float b) { return make_float2(a, b); }

// fp16 pack/unpack (round-to-nearest; validated R15/R16: absmax 0.0)
__device__ __forceinline__ unsigned pack2h(float a, float b) {
    __half2 h = __float22half2_rn(make_float2(a, b));
    union { __half2 h; unsigned u; } c; c.h = h; return c.u;
}
__device__ __forceinline__ float2 unpack2h(unsigned u) {
    union { unsigned u; __half2 h; } c; c.u = u;
    return make_float2(__half2float(__low2half(c.h)), __half2float(__high2half(c.h)));
}

__device__ __forceinline__ float det3(float a0, float a1, float a2,
                                      float b0, float b1, float b2,
                                      float c0, float c1, float c2) {
    return a0 * (b1 * c2 - b2 * c1)
         - a1 * (b0 * c2 - b2 * c0)
         + a2 * (b0 * c1 - b1 * c0);
}

// FINAL (R16 restore, best measured 41.3 us): single data pass; 4 samples
// per wave (16-lane groups); fp32 moment accumulation; fp16-compressed
// point set pinned in registers across the 16-lane-amortized Horn solve;
// residuals from registers; DPP butterfly reductions; bounds(256,4).
// R18 (2 samples/wave, higher occupancy) regressed: per-sample wave-level
// overhead doubled and outweighed the latency-hiding gain. This config is
// the measured floor of the bracketed design space.
__global__ __launch_bounds__(256, 4) void pa_mpjpe_kernel(
    const float* __restrict__ outp,   // (N,K,3) output
    const float* __restrict__ tgtp,   // (N,K,3) target
    float* __restrict__ block_sums,
    int nsamp)
{
    const int tid  = threadIdx.x;
    const int lane = tid & 63;
    const int wid  = tid >> 6;
    const int l16  = lane & 15;
    const int s_l  = wid * SPWV + (lane >> 4);   // local sample 0..15
    int s = blockIdx.x * SPB + s_l;
    const bool valid = (s < nsamp);
    if (!valid) s = 0;                           // clamp; zeroed later

    __shared__ float momT[SPB][17];
    __shared__ float prm[SPB][13];
    __shared__ float shs[SPB];

    const float* tb = tgtp + (size_t)s * FPS;
    const float* ob = outp + (size_t)s * FPS;

    // ---- load points, accumulate fp32 moments, pack to half2 ----
    float2 P0 = f2(0,0), P1 = f2(0,0), P2 = f2(0,0), P3 = f2(0,0);
    float2 P4 = f2(0,0), P5 = f2(0,0), P6 = f2(0,0), P7 = f2(0,0);
    float2 Q  = f2(0,0);

#define DECLPT(k) unsigned uT_##k = 0u, uM_##k = 0u, uO_##k = 0u;
#define LOADACC(k, P) {                                                     \
    const int idx_ = 3 * (P);                                               \
    const float t0 = tb[idx_+0], t1 = tb[idx_+1], t2 = tb[idx_+2];          \
    const float o0 = ob[idx_+0], o1 = ob[idx_+1], o2 = ob[idx_+2];          \
    P0 += f2(t0, t1);                                                       \
    P1 += f2(t2, o0);                                                       \
    P2 += f2(o1, o2);                                                       \
    P3 += f2(t0, t0) * f2(o0, o1);                                          \
    P4 += f2(t0, t1) * f2(o2, o0);                                          \
    P5 += f2(t1, t1) * f2(o1, o2);                                          \
    P6 += f2(t2, t2) * f2(o0, o1);                                          \
    P7 += f2(t2, t0) * f2(o2, t0);                                          \
    Q  += f2(t1, t2) * f2(t1, t2);                                          \
    uT_##k = pack2h(t0, t1);                                                \
    uM_##k = pack2h(t2, o0);                                                \
    uO_##k = pack2h(o1, o2);                                                \
}
#define PINPT(k) PINU(uT_##k); PINU(uM_##k); PINU(uO_##k);

    DECLPT(0) DECLPT(1) DECLPT(2) DECLPT(3)
    DECLPT(4) DECLPT(5) DECLPT(6) DECLPT(7)
    DECLPT(8)

    LOADACC(0, l16 +   0)
    LOADACC(1, l16 +  16)
    LOADACC(2, l16 +  32)
    LOADACC(3, l16 +  48)
    LOADACC(4, l16 +  64)
    LOADACC(5, l16 +  80)
    LOADACC(6, l16 +  96)
    LOADACC(7, l16 + 112)
    if (l16 < 5) {
        LOADACC(8, 128 + l16)
    }

    // pin packed points: live across butterfly + solve + barriers
    PINPT(0) PINPT(1) PINPT(2) PINPT(3)
    PINPT(4) PINPT(5) PINPT(6) PINPT(7)
    PINPT(8)

    float red[16];
    red[0]  = P0.x; red[1]  = P0.y; red[2]  = P1.x; red[3]  = P1.y;
    red[4]  = P2.x; red[5]  = P2.y; red[6]  = P3.x; red[7]  = P3.y;
    red[8]  = P4.x; red[9]  = P4.y; red[10] = P5.x; red[11] = P5.y;
    red[12] = P6.x; red[13] = P6.y; red[14] = P7.x; red[15] = P7.y + Q.x + Q.y;

    // ---- 4-stage value-splitting butterfly within 16-lane group ----
    float v8[8];
    {
        const bool b = (lane & 1);
        #pragma unroll
        for (int m = 0; m < 8; ++m) {
            const float snd = b ? red[2 * m] : red[2 * m + 1];
            const float rcv = DPP_XOR1(snd);
            v8[m] = (b ? red[2 * m + 1] : red[2 * m]) + rcv;
        }
    }
    float v4_[4];
    {
        const bool b = ((lane >> 1) & 1);
        #pragma unroll
        for (int m = 0; m < 4; ++m) {
            const float snd = b ? v8[2 * m] : v8[2 * m + 1];
            const float rcv = DPP_XOR2(snd);
            v4_[m] = (b ? v8[2 * m + 1] : v8[2 * m]) + rcv;
        }
    }
    float v2_[2];
    {
        const bool b = ((lane >> 2) & 1);
        #pragma unroll
        for (int m = 0; m < 2; ++m) {
            const float snd = b ? v4_[2 * m] : v4_[2 * m + 1];
            const float rcv = __shfl_xor(snd, 4, 64);
            v2_[m] = (b ? v4_[2 * m + 1] : v4_[2 * m]) + rcv;
        }
    }
    float v1;
    {
        const bool b = ((lane >> 3) & 1);
        const float snd = b ? v2_[0] : v2_[1];
        const float rcv = __shfl_xor(snd, 8, 64);
        v1 = (b ? v2_[1] : v2_[0]) + rcv;
    }

    momT[s_l][l16] = v1;
    __syncthreads();

    // ---- solve: wave 0, lanes 0..15, one sample each (16x amortized) ----
    if (wid == 0 && lane < SPB && (blockIdx.x * SPB + lane) < nsamp) {
        float m_[16];
        #pragma unroll
        for (int j = 0; j < 16; ++j) m_[j] = momT[lane][j];

        const float invK = 1.0f / (float)KPTS;
        const float mu1x = m_[0] * invK, mu1y = m_[1] * invK, mu1z = m_[2] * invK;
        const float mu2x = m_[3] * invK, mu2y = m_[4] * invK, mu2z = m_[5] * invK;

        const float Sxx = m_[6]  - m_[0] * m_[3] * invK;
        const float Sxy = m_[7]  - m_[0] * m_[4] * invK;
        const float Sxz = m_[8]  - m_[0] * m_[5] * invK;
        const float Syx = m_[9]  - m_[1] * m_[3] * invK;
        const float Syy = m_[10] - m_[1] * m_[4] * invK;
        const float Syz = m_[11] - m_[1] * m_[5] * invK;
        const float Szx = m_[12] - m_[2] * m_[3] * invK;
        const float Szy = m_[13] - m_[2] * m_[4] * invK;
        const float Szz = m_[14] - m_[2] * m_[5] * invK;
        const float var1 = m_[15] - (m_[0] * m_[0] + m_[1] * m_[1] + m_[2] * m_[2]) * invK;

        const float N00 = Sxx + Syy + Szz;
        const float N01 = Syz - Szy, N02 = Szx - Sxz, N03 = Sxy - Syx;
        const float N11 = Sxx - Syy - Szz, N12 = Sxy + Syx, N13 = Szx + Sxz;
        const float N22 = -Sxx + Syy - Szz, N23 = Syz + Szy;
        const float N33 = -Sxx - Syy + Szz;

        const float trKtK = Sxx * Sxx + Sxy * Sxy + Sxz * Sxz
                          + Syx * Syx + Syy * Syy + Syz * Syz
                          + Szx * Szx + Szy * Szy + Szz * Szz;
        const float c2 = -2.0f * trKtK;
        const float detK = det3(Sxx, Sxy, Sxz, Syx, Syy, Syz, Szx, Szy, Szz);
        const float c1 = -8.0f * detK;
        const float c0 =
              N00 * det3(N11, N12, N13, N12, N22, N23, N13, N23, N33)
            - N01 * det3(N01, N12, N13, N02, N22, N23, N03, N23, N33)
            + N02 * det3(N01, N11, N13, N02, N12, N23, N03, N13, N33)
            - N03 * det3(N01, N11, N12, N02, N12, N22, N03, N13, N23);

        float lam = sqrtf(fmaxf(3.0f * trKtK, 0.0f));
        #pragma unroll
        for (int it = 0; it < 10; ++it) {
            const float l2 = lam * lam;
            const float P  = (l2 + c2) * l2 + c1 * lam + c0;
            const float Pp = (4.0f * l2 + 2.0f * c2) * lam + c1;
            lam -= P / Pp;
        }

        const float M00 = N00 - lam, M11 = N11 - lam, M22 = N22 - lam, M33 = N33 - lam;
        const float a0 =  det3(M11, N12, N13, N12, M22, N23, N13, N23, M33);
        const float a1 = -det3(N01, N12, N13, N02, M22, N23, N03, N23, M33);
        const float a2 =  det3(N01, M11, N13, N02, N12, N23, N03, N13, M33);
        const float a3 = -det3(N01, M11, N12, N02, N12, M22, N03, N13, N23);
        const float b0 = -det3(N01, N02, N03, N12, M22, N23, N13, N23, M33);
        const float b1 =  det3(M00, N02, N03, N02, M22, N23, N03, N23, M33);
        const float b2 = -det3(M00, N01, N03, N02, N12, N23, N03, N13, M33);
        const float b3 =  det3(M00, N01, N02, N02, N12, M22, N03, N13, N23);
        const float na = a0 * a0 + a1 * a1 + a2 * a2 + a3 * a3;
        const float nb = b0 * b0 + b1 * b1 + b2 * b2 + b3 * b3;
        const bool pa_ = (na >= nb);
        float qw = pa_ ? a0 : b0;
        float qx = pa_ ? a1 : b1;
        float qy = pa_ ? a2 : b2;
        float qz = pa_ ? a3 : b3;
        const float qn = rsqrtf(fmaxf(qw * qw + qx * qx + qy * qy + qz * qz, 1e-30f));
        qw *= qn; qx *= qn; qy *= qn; qz *= qn;

        const float R00 = 1.0f - 2.0f * (qy * qy + qz * qz);
        const float R01 = 2.0f * (qx * qy - qw * qz);
        const float R02 = 2.0f * (qx * qz + qw * qy);
        const float R10 = 2.0f * (qx * qy + qw * qz);
        const float R11 = 1.0f - 2.0f * (qx * qx + qz * qz);
        const float R12 = 2.0f * (qy * qz - qw * qx);
        const float R20 = 2.0f * (qx * qz - qw * qy);
        const float R21 = 2.0f * (qy * qz + qw * qx);
        const float R22 = 1.0f - 2.0f * (qx * qx + qy * qy);

        const float trRK = R00 * Sxx + R01 * Syx + R02 * Szx
                         + R10 * Sxy + R11 * Syy + R12 * Szy
                         + R20 * Sxz + R21 * Syz + R22 * Szz;
        const float scale = trRK / var1;

        const float tx = mu2x - scale * (R00 * mu1x + R01 * mu1y + R02 * mu1z);
        const float ty = mu2y - scale * (R10 * mu1x + R11 * mu1y + R12 * mu1z);
        const float tz = mu2z - scale * (R20 * mu1x + R21 * mu1y + R22 * mu1z);

        prm[lane][0] = scale * R00; prm[lane][1] = scale * R01; prm[lane][2] = scale * R02;
        prm[lane][3] = scale * R10; prm[lane][4] = scale * R11; prm[lane][5] = scale * R12;
        prm[lane][6] = scale * R20; prm[lane][7] = scale * R21; prm[lane][8] = scale * R22;
        prm[lane][9] = tx; prm[lane][10] = ty; prm[lane][11] = tz;
    }
    __syncthreads();

    // ---- residuals from fp16-packed pinned registers (no second pass) ----
    const float2 rA = f2(prm[s_l][0], prm[s_l][3]);   // (sR00, sR10)
    const float2 rB = f2(prm[s_l][1], prm[s_l][4]);   // (sR01, sR11)
    const float2 rC = f2(prm[s_l][2], prm[s_l][5]);   // (sR02, sR12)
    const float sR20 = prm[s_l][6], sR21 = prm[s_l][7], sR22 = prm[s_l][8];
    const float2 txy = f2(prm[s_l][9], prm[s_l][10]);
    const float tz = prm[s_l][11];

    float rsum = 0.0f;
#define RESPT(k)                                                            \
    {                                                                       \
        const float2 pT = unpack2h(uT_##k);   /* t0, t1 */                  \
        const float2 pM = unpack2h(uM_##k);   /* t2, o0 */                  \
        const float2 pO = unpack2h(uO_##k);   /* o1, o2 */                  \
        float2 axy = txy;                                                   \
        axy += rA * f2(pT.x, pT.x);                                         \
        axy += rB * f2(pT.y, pT.y);                                         \
        axy += rC * f2(pM.x, pM.x);                                         \
        const float az = fmaf(sR20, pT.x, fmaf(sR21, pT.y, fmaf(sR22, pM.x, tz))); \
        const float2 dxy = f2(pM.y, pO.x) - axy;                            \
        const float dz = pO.y - az;                                         \
        const float ns = fmaf(dxy.x, dxy.x, fmaf(dxy.y, dxy.y, dz * dz));   \
        rsum += sqrtf(ns);                                                  \
    }

    RESPT(0) RESPT(1) RESPT(2) RESPT(3)
    RESPT(4) RESPT(5) RESPT(6) RESPT(7)
    if (l16 < 5) { RESPT(8) }

    rsum = valid ? rsum : 0.0f;

    rsum += DPP_XOR1(rsum);
    rsum += DPP_XOR2(rsum);
    rsum += __shfl_xor(rsum, 4, 64);
    rsum += __shfl_xor(rsum, 8, 64);

    if (l16 == 0) shs[s_l] = rsum;
    __syncthreads();
    if (tid == 0) {
        float b = 0.0f;
        #pragma unroll
        for (int i = 0; i < SPB; ++i) b += shs[i];
        block_sums[blockIdx.x] = b;
    }
}

// Deterministic final reduction: one block, fixed order, 4-way ILP.
__global__ __launch_bounds__(256) void pa_reduce_kernel(
    const float* __restrict__ block_sums, int n,
    float* __restrict__ out, float inv_total)
{
    __shared__ float sh[4];
    float a0 = 0.f, a1 = 0.f, a2 = 0.f, a3 = 0.f;
    for (int i = (int)threadIdx.x * 4; i < n; i += 1024) {
        if (i + 0 < n) a0 += block_sums[i + 0];
        if (i + 1 < n) a1 += block_sums[i + 1];
        if (i + 2 < n) a2 += block_sums[i + 2];
        if (i + 3 < n) a3 += block_sums[i + 3];
    }
    float v = (a0 + a1) + (a2 + a3);
    #pragma unroll
    for (int off = 32; off >= 1; off >>= 1) v += __shfl_xor(v, off, 64);
    const int lane = threadIdx.x & 63;
    const int wid  = threadIdx.x >> 6;
    if (lane == 0) sh[wid] = v;
    __syncthreads();
    if (threadIdx.x == 0) out[0] = (sh[0] + sh[1] + sh[2] + sh[3]) * inv_total;
}

extern "C" void kernel_launch(void* const* d_in, const int* in_sizes, int n_in,
                              void* d_out, int out_size, void* d_ws, size_t ws_size,
                              hipStream_t stream) {
    const float* outp = (const float*)d_in[0];   // "output"
    const float* tgtp = (const float*)d_in[1];   // "target"
    const int nsamp   = in_sizes[0] / FPS;
    const int nblocks = (nsamp + SPB - 1) / SPB;

    float* bsums = (float*)d_ws;

    pa_mpjpe_kernel<<<nblocks, 256, 0, stream>>>(outp, tgtp, bsums, nsamp);
    pa_reduce_kernel<<<1, 256, 0, stream>>>(
        bsums, nblocks, (float*)d_out,
        1.0f / ((float)nsamp * (float)KPTS));
}